// Round 4
// baseline (521.324 us; speedup 1.0000x reference)
//
#include <hip/hip_runtime.h>

#define N_ 16
#define C_ 256
#define F_ 64
#define T_ 256

typedef float f32x4 __attribute__((ext_vector_type(4)));

__device__ __forceinline__ float clampf(float v, float lo, float hi) {
    return fminf(fmaxf(v, lo), hi);
}

// integer code k = clip(rint(x*scale), -128, 127), returned as float
__device__ __forceinline__ float qcode(float x, float scale) {
    return clampf(rintf(x * scale), -128.f, 127.f);
}

// ---------------------------------------------------------------------------
// k1: freq dwconv + q + SSN + q -> aux int8 codes; freq-sum -> mean int8.
// R4: F-SPLIT. Block = 4 waves = 2 planes x 2 freq-halves. Each wave owns 32
// freq rows of one (n,c) plane (lane = 4 consecutive t, float4 loads), keeps
// the 4-row double-buffered pipeline, and contributes a partial freq-sum;
// partner waves combine via 4 KiB LDS. Grid 2048 = 8 blocks/CU (was 4) ->
// 2x wave-level parallelism for latency hiding. +1 halo row read per wave.
// NOTE: no nontemporal hints — NT bypass races the harness's cached
// restore/poison ops (R4 post-timing divergence).
// ---------------------------------------------------------------------------
#define K1ROW(XM, X0, XN, FROW)                                                \
    {                                                                          \
        float ka0, ka1, ka2, ka3;                                              \
        {                                                                      \
            float conv = (XM).x * w0 + (X0).x * w1c + (XN).x * w2;             \
            float q1c = clampf(rintf(conv * 16.f), -128.f, 127.f);             \
            ka0 = clampf(rintf(fmaf(q1c, m, bc)), -128.f, 127.f);              \
        }                                                                      \
        {                                                                      \
            float conv = (XM).y * w0 + (X0).y * w1c + (XN).y * w2;             \
            float q1c = clampf(rintf(conv * 16.f), -128.f, 127.f);             \
            ka1 = clampf(rintf(fmaf(q1c, m, bc)), -128.f, 127.f);              \
        }                                                                      \
        {                                                                      \
            float conv = (XM).z * w0 + (X0).z * w1c + (XN).z * w2;             \
            float q1c = clampf(rintf(conv * 16.f), -128.f, 127.f);             \
            ka2 = clampf(rintf(fmaf(q1c, m, bc)), -128.f, 127.f);              \
        }                                                                      \
        {                                                                      \
            float conv = (XM).w * w0 + (X0).w * w1c + (XN).w * w2;             \
            float q1c = clampf(rintf(conv * 16.f), -128.f, 127.f);             \
            ka3 = clampf(rintf(fmaf(q1c, m, bc)), -128.f, 127.f);              \
        }                                                                      \
        const int i0 = (int)ka0, i1 = (int)ka1, i2 = (int)ka2, i3 = (int)ka3;  \
        s0 += i0; s1 += i1; s2 += i2; s3 += i3;                                \
        char4 cv;                                                              \
        cv.x = (signed char)i0; cv.y = (signed char)i1;                        \
        cv.z = (signed char)i2; cv.w = (signed char)i3;                        \
        *(char4*)(ap + (FROW) * T_) = cv;                                      \
    }

__global__ __launch_bounds__(256) void aux_mean_kernel(
    const float* __restrict__ x,
    const float* __restrict__ wf,
    const float* __restrict__ ssn_g,
    const float* __restrict__ ssn_b,
    const float* __restrict__ ssn_mu,
    const float* __restrict__ ssn_va,
    signed char* __restrict__ aux_s8,
    signed char* __restrict__ mean_s8)
{
    const int wid  = threadIdx.x >> 6;           // 0..3
    const int lane = threadIdx.x & 63;
    const int pl   = blockIdx.x * 2 + (wid >> 1);  // plane = n*C + c
    const int fh   = wid & 1;                    // freq half: rows fh*32..fh*32+31
    const int c    = pl & (C_ - 1);
    const int t0   = lane * 4;
    const int fbase = fh * 32;

    const f32x4* xp = (const f32x4*)(x + (size_t)pl * (F_ * T_) + t0);
    signed char*  ap = aux_s8 + (size_t)pl * (F_ * T_) + t0;

    const float w0  = qcode(wf[c * 3 + 0], 128.f) * (1.f / 128.f);
    const float w1c = qcode(wf[c * 3 + 1], 128.f) * (1.f / 128.f);
    const float w2  = qcode(wf[c * 3 + 2], 128.f) * (1.f / 128.f);

    f32x4 zero; zero.x = 0.f; zero.y = 0.f; zero.z = 0.f; zero.w = 0.f;
    f32x4 xm   = fh ? xp[(fbase - 1) * (T_ / 4)] : zero;   // halo row below
    f32x4 cur0 = xp[(fbase + 0) * (T_ / 4)];
    f32x4 cur1 = xp[(fbase + 1) * (T_ / 4)];
    f32x4 cur2 = xp[(fbase + 2) * (T_ / 4)];
    f32x4 cur3 = xp[(fbase + 3) * (T_ / 4)];
    int s0 = 0, s1 = 0, s2 = 0, s3 = 0;

    #pragma unroll
    for (int g2 = 0; g2 < 2; ++g2) {             // SSN groups fh*2 + g2
        const int cs = c * 4 + fh * 2 + g2;
        const float m  = qcode(ssn_g[cs] * rsqrtf(ssn_va[cs] + 1e-5f), 128.f) * (1.f / 128.f);
        const float bc = qcode(ssn_b[cs] - ssn_mu[cs] * m, 16.f);   // bias CODE
        #pragma unroll
        for (int bb = 0; bb < 4; ++bb) {
            const int rel = g2 * 16 + bb * 4;    // 0,4,...,28 within the half
            f32x4 nxt0, nxt1, nxt2, nxt3;
            if (rel + 4 < 32) {                  // compile-time (unrolled)
                nxt0 = xp[(fbase + rel + 4) * (T_ / 4)];
                nxt1 = xp[(fbase + rel + 5) * (T_ / 4)];
                nxt2 = xp[(fbase + rel + 6) * (T_ / 4)];
                nxt3 = xp[(fbase + rel + 7) * (T_ / 4)];
            } else {                             // tail: only halo row above
                nxt0 = (fh == 0) ? xp[32 * (T_ / 4)] : zero;  // wave-uniform
                nxt1 = zero; nxt2 = zero; nxt3 = zero;
            }
            K1ROW(xm,   cur0, cur1, fbase + rel + 0);
            K1ROW(cur0, cur1, cur2, fbase + rel + 1);
            K1ROW(cur1, cur2, cur3, fbase + rel + 2);
            K1ROW(cur2, cur3, nxt0, fbase + rel + 3);
            xm = cur3;
            cur0 = nxt0; cur1 = nxt1; cur2 = nxt2; cur3 = nxt3;
        }
    }

    // ---- combine partner halves' partial sums; fh==0 waves write mean ----
    __shared__ int4 ps[4][64];                   // 4 KiB
    int4 mine; mine.x = s0; mine.y = s1; mine.z = s2; mine.w = s3;
    ps[wid][lane] = mine;
    __syncthreads();
    if (fh == 0) {
        const int4 o = ps[wid + 1][lane];
        s0 += o.x; s1 += o.y; s2 += o.z; s3 += o.w;
        char4 mv;
        mv.x = (signed char)(int)clampf(rintf((float)s0 * (1.f / 64.f)), -128.f, 127.f);
        mv.y = (signed char)(int)clampf(rintf((float)s1 * (1.f / 64.f)), -128.f, 127.f);
        mv.z = (signed char)(int)clampf(rintf((float)s2 * (1.f / 64.f)), -128.f, 127.f);
        mv.w = (signed char)(int)clampf(rintf((float)s3 * (1.f / 64.f)), -128.f, 127.f);
        *(char4*)(mean_s8 + (size_t)pl * T_ + t0) = mv;
    }
}

// ---------------------------------------------------------------------------
// k2: temporal conv + q + bn2 + q + relu + 1x1 conv + q on the (N,C,1,T) mean.
// z transposed to [C][TT+4] so phase-2 inner reads are broadcast ds_read_b128.
// Phase-2 weight row loaded as float4 (verified R1).
// ---------------------------------------------------------------------------
#define TT_ 16
#define ZP_ (TT_ + 4)
__global__ __launch_bounds__(256) void mean_path_kernel(
    const signed char* __restrict__ mean_s8,
    const float* __restrict__ wt,
    const float* __restrict__ g2,
    const float* __restrict__ b2,
    const float* __restrict__ mu2,
    const float* __restrict__ va2,
    const float* __restrict__ w1,
    signed char* __restrict__ y_s8)
{
    const int n = blockIdx.x >> 4;
    const int tt = (blockIdx.x & 15) * TT_;
    const int tid = threadIdx.x;

    __shared__ float z[C_][ZP_];   // 20 KiB, rows 80B apart (16B aligned)

    {   // phase 1: c = tid
        const int c = tid;
        const float wq0 = qcode(wt[c * 3 + 0], 128.f) * (1.f / 128.f);
        const float wq1 = qcode(wt[c * 3 + 1], 128.f) * (1.f / 128.f);
        const float wq2 = qcode(wt[c * 3 + 2], 128.f) * (1.f / 128.f);
        const float m2 = qcode(g2[c] * rsqrtf(va2[c] + 1e-5f), 128.f) * (1.f / 128.f);
        const float bc2 = qcode(b2[c] - mu2[c] * m2, 16.f);   // bias code
        const signed char* mp = mean_s8 + (n * C_ + c) * T_;
        #pragma unroll
        for (int j = 0; j < TT_; ++j) {
            const int t = tt + j;
            const float a    = (t > 0)      ? (float)mp[t - 1] : 0.f;   // codes
            const float bmid =                (float)mp[t];
            const float d    = (t < T_ - 1) ? (float)mp[t + 1] : 0.f;
            // conv on values = (code/16); q(.,16) code = clamp(rint(conv*16))
            float tcc = a * wq0 + bmid * wq1 + d * wq2;          // = conv*16
            float q1c = clampf(rintf(tcc), -128.f, 127.f);       // code of q(tc)
            float v   = clampf(rintf(fmaf(q1c, m2, bc2)), -128.f, 127.f); // code
            v = fmaxf(v, 0.f);               // relu on codes
            z[c][j] = v * (1.f / 16.f);      // value for the 1x1 dot
        }
    }
    __syncthreads();
    {   // phase 2: o = tid
        const int o = tid;
        float acc[TT_];
        #pragma unroll
        for (int j = 0; j < TT_; ++j) acc[j] = 0.f;
        const float* wrow = w1 + o * C_;
        for (int cbase = 0; cbase < C_; cbase += 4) {
            const f32x4 wv4 = *(const f32x4*)(wrow + cbase);
            const float wq[4] = {
                qcode(wv4.x, 128.f) * (1.f / 128.f),
                qcode(wv4.y, 128.f) * (1.f / 128.f),
                qcode(wv4.z, 128.f) * (1.f / 128.f),
                qcode(wv4.w, 128.f) * (1.f / 128.f)
            };
            #pragma unroll
            for (int u = 0; u < 4; ++u) {
                const float wv = wq[u];
                const f32x4 za = *(const f32x4*)&z[cbase + u][0];
                const f32x4 zb = *(const f32x4*)&z[cbase + u][4];
                const f32x4 zc = *(const f32x4*)&z[cbase + u][8];
                const f32x4 zd = *(const f32x4*)&z[cbase + u][12];
                acc[0]  += za.x * wv; acc[1]  += za.y * wv; acc[2]  += za.z * wv; acc[3]  += za.w * wv;
                acc[4]  += zb.x * wv; acc[5]  += zb.y * wv; acc[6]  += zb.z * wv; acc[7]  += zb.w * wv;
                acc[8]  += zc.x * wv; acc[9]  += zc.y * wv; acc[10] += zc.z * wv; acc[11] += zc.w * wv;
                acc[12] += zd.x * wv; acc[13] += zd.y * wv; acc[14] += zd.z * wv; acc[15] += zd.w * wv;
            }
        }
        signed char* yp = y_s8 + (n * C_ + o) * T_ + tt;
        #pragma unroll
        for (int j = 0; j < TT_; ++j) {
            yp[j] = (signed char)(int)qcode(acc[j], 16.f);
        }
    }
}

// ---------------------------------------------------------------------------
// k3: out = relu(quant(aux + y)) = clamp(ka + ky, 0, 127) / 16 -> fp32.
// R4: F-SPLIT like k1 — wave owns 32 rows of one plane (rows independent),
// 8-row double-buffered batches. Grid 2048 = 8 blocks/CU (was 4).
// ---------------------------------------------------------------------------
__global__ __launch_bounds__(256) void combine_kernel(
    const signed char* __restrict__ aux_s8,
    const signed char* __restrict__ y_s8,
    float* __restrict__ out)
{
    const int wid  = threadIdx.x >> 6;
    const int lane = threadIdx.x & 63;
    const int pl   = blockIdx.x * 2 + (wid >> 1);
    const int fh   = wid & 1;
    const int t0   = lane * 4;

    const char4 yk = *(const char4*)(y_s8 + (size_t)pl * T_ + t0);
    const int y0 = yk.x, y1 = yk.y, y2 = yk.z, y3 = yk.w;

    const int* ap = (const int*)(aux_s8 + (size_t)pl * (F_ * T_) + (size_t)fh * 32 * T_ + t0);
    f32x4* op = (f32x4*)(out + (size_t)pl * (F_ * T_) + (size_t)fh * 32 * T_ + t0);

    int cura[8], nxta[8];
    #pragma unroll
    for (int i = 0; i < 8; ++i) cura[i] = ap[i * (T_ / 4)];

    #pragma unroll
    for (int b = 0; b < 4; ++b) {
        if (b < 3) {                     // compile-time (fully unrolled)
            #pragma unroll
            for (int i = 0; i < 8; ++i)
                nxta[i] = ap[(b * 8 + 8 + i) * (T_ / 4)];
        }
        #pragma unroll
        for (int i = 0; i < 8; ++i) {
            const int u = cura[i];
            const int o0 = min(127, max(0, ((int)(signed char)(u))       + y0));
            const int o1 = min(127, max(0, ((int)(signed char)(u >> 8))  + y1));
            const int o2 = min(127, max(0, ((int)(signed char)(u >> 16)) + y2));
            const int o3 = min(127, max(0, (u >> 24)                     + y3));
            f32x4 ov;
            ov.x = (float)o0 * (1.f / 16.f);
            ov.y = (float)o1 * (1.f / 16.f);
            ov.z = (float)o2 * (1.f / 16.f);
            ov.w = (float)o3 * (1.f / 16.f);
            op[(b * 8 + i) * (T_ / 4)] = ov;
        }
        #pragma unroll
        for (int i = 0; i < 8; ++i) cura[i] = nxta[i];
    }
}

extern "C" void kernel_launch(void* const* d_in, const int* in_sizes, int n_in,
                              void* d_out, int out_size, void* d_ws, size_t ws_size,
                              hipStream_t stream) {
    const float* x       = (const float*)d_in[0];
    const float* w_freq  = (const float*)d_in[1];
    const float* ssn_g   = (const float*)d_in[2];
    const float* ssn_b   = (const float*)d_in[3];
    const float* ssn_mu  = (const float*)d_in[4];
    const float* ssn_va  = (const float*)d_in[5];
    const float* w_temp  = (const float*)d_in[6];
    const float* g2      = (const float*)d_in[7];
    const float* b2      = (const float*)d_in[8];
    const float* mu2     = (const float*)d_in[9];
    const float* va2     = (const float*)d_in[10];
    const float* w_1x1   = (const float*)d_in[11];
    float* out = (float*)d_out;

    signed char* aux_s8  = (signed char*)d_ws;                        // 64 MiB
    signed char* mean_s8 = aux_s8 + (size_t)N_ * C_ * F_ * T_;        // 1 MiB
    signed char* y_s8    = mean_s8 + (size_t)N_ * C_ * T_;            // 1 MiB

    dim3 blk(256);
    aux_mean_kernel<<<dim3(N_ * C_ / 2), blk, 0, stream>>>(
        x, w_freq, ssn_g, ssn_b, ssn_mu, ssn_va, aux_s8, mean_s8);
    mean_path_kernel<<<dim3(N_ * (T_ / TT_)), blk, 0, stream>>>(
        mean_s8, w_temp, g2, b2, mu2, va2, w_1x1, y_s8);
    combine_kernel<<<dim3(N_ * C_ / 2), blk, 0, stream>>>(
        aux_s8, y_s8, out);
}